// Round 1
// baseline (398.547 us; speedup 1.0000x reference)
//
#include <hip/hip_runtime.h>

#define NBLK 1024
#define SBAT 256
#define SBLK 8

// Phase 1: for each (block i, batch b) compute
//   C_i = A_i^{-1} B_{i-1}   (C_0 = 0)
//   d_i = A_i^{-1} v_i
// via Gauss-Jordan elimination with 8 lanes per system (lane = row),
// 8 systems per wave64. A is diagonally dominant -> no pivoting needed.
__global__ __launch_bounds__(256) void pcr_phase1(
    const float* __restrict__ A, const float* __restrict__ B,
    const float* __restrict__ v, float* __restrict__ C, float* __restrict__ D) {
  const int lane = threadIdx.x & 63;
  const int wib  = threadIdx.x >> 6;
  const int s = lane >> 3;       // system within wave (0..7)
  const int r = lane & 7;        // row (0..7)
  const long w  = (long)blockIdx.x * 4 + wib;  // global wave id
  const long t0 = w * 8;                        // first task of this wave
  const int i = (int)(t0 >> 8);                 // time block (t0/256)
  const int b = (int)(t0 & 255) + s;            // batch index
  const long sysid = (long)i * SBAT + b;

  float a[8], c[8], vv;
  {
    const float4* A4 = (const float4*)A;
    const long ab = (sysid * 8 + r) * 2;
    float4 lo = A4[ab], hi = A4[ab + 1];
    a[0]=lo.x; a[1]=lo.y; a[2]=lo.z; a[3]=lo.w;
    a[4]=hi.x; a[5]=hi.y; a[6]=hi.z; a[7]=hi.w;
  }
  if (i > 0) {
    const float4* B4 = (const float4*)B;
    const long bb = (((long)(i - 1) * SBAT + b) * 8 + r) * 2;
    float4 lo = B4[bb], hi = B4[bb + 1];
    c[0]=lo.x; c[1]=lo.y; c[2]=lo.z; c[3]=lo.w;
    c[4]=hi.x; c[5]=hi.y; c[6]=hi.z; c[7]=hi.w;
  } else {
    #pragma unroll
    for (int j = 0; j < 8; ++j) c[j] = 0.f;
  }
  vv = v[(long)b * (NBLK * SBLK) + i * SBLK + r];

  // Gauss-Jordan: reduce a -> I, c -> A^{-1}B, vv -> A^{-1}v.
  #pragma unroll
  for (int k = 0; k < 8; ++k) {
    const float piv  = __shfl(a[k], k, 8);
    const float invp = 1.0f / piv;
    if (r == k) {
      #pragma unroll
      for (int j = 0; j < 8; ++j) { a[j] *= invp; c[j] *= invp; }
      vv *= invp;
    }
    const float f  = (r == k) ? 0.0f : a[k];   // read before update
    const float vk = __shfl(vv, k, 8);
    #pragma unroll
    for (int j = 0; j < 8; ++j) {
      const float akj = __shfl(a[j], k, 8);    // scaled pivot row
      const float ckj = __shfl(c[j], k, 8);
      a[j] = fmaf(-f, akj, a[j]);
      c[j] = fmaf(-f, ckj, c[j]);
    }
    vv = fmaf(-f, vk, vv);
  }

  float4 lo, hi;
  lo.x=c[0]; lo.y=c[1]; lo.z=c[2]; lo.w=c[3];
  hi.x=c[4]; hi.y=c[5]; hi.z=c[6]; hi.w=c[7];
  float4* C4 = (float4*)C;
  const long cb = (sysid * 8 + r) * 2;
  C4[cb] = lo; C4[cb + 1] = hi;
  D[sysid * 8 + r] = vv;
}

// Phase 2: serial recurrence x_i = d_i - C_i x_{i-1}.
// 8 lanes per system (lane = row), 8 systems per wave, 32 waves total.
// NB-deep register ring buffer prefetch (fully unrolled -> stays in VGPRs).
__global__ __launch_bounds__(64) void pcr_phase2(
    const float* __restrict__ C, const float* __restrict__ D,
    float* __restrict__ out) {
  const int lane = threadIdx.x & 63;
  const int s = lane >> 3, r = lane & 7;
  const int sys = blockIdx.x * 8 + s;
  const float4* C4 = (const float4*)C;

  constexpr int NB = 16;
  float4 bl[NB], bh[NB];
  float  bd[NB];
  #pragma unroll
  for (int j = 0; j < NB; ++j) {
    const long cb = (((long)j * SBAT + sys) * 8 + r) * 2;
    bl[j] = C4[cb]; bh[j] = C4[cb + 1];
    bd[j] = D[((long)j * SBAT + sys) * 8 + r];
  }

  float xprev = 0.f;
  for (int i0 = 0; i0 < NBLK; i0 += NB) {
    #pragma unroll
    for (int j = 0; j < NB; ++j) {
      const int i = i0 + j;
      const float4 cl = bl[j], ch = bh[j];
      const float dd = bd[j];
      const int ip = i + NB;
      if (ip < NBLK) {  // refill the slot we just consumed, NB iters ahead
        const long cb = (((long)ip * SBAT + sys) * 8 + r) * 2;
        bl[j] = C4[cb]; bh[j] = C4[cb + 1];
        bd[j] = D[((long)ip * SBAT + sys) * 8 + r];
      }
      const float x0=__shfl(xprev,0,8), x1=__shfl(xprev,1,8),
                  x2=__shfl(xprev,2,8), x3=__shfl(xprev,3,8),
                  x4=__shfl(xprev,4,8), x5=__shfl(xprev,5,8),
                  x6=__shfl(xprev,6,8), x7=__shfl(xprev,7,8);
      float acc0 = cl.x * x0;
      acc0 = fmaf(cl.z, x2, acc0);
      acc0 = fmaf(ch.x, x4, acc0);
      acc0 = fmaf(ch.z, x6, acc0);
      float acc1 = cl.y * x1;
      acc1 = fmaf(cl.w, x3, acc1);
      acc1 = fmaf(ch.y, x5, acc1);
      acc1 = fmaf(ch.w, x7, acc1);
      const float x = dd - acc0 - acc1;
      out[(long)sys * (NBLK * SBLK) + i * SBLK + r] = x;
      xprev = x;
    }
  }
}

extern "C" void kernel_launch(void* const* d_in, const int* in_sizes, int n_in,
                              void* d_out, int out_size, void* d_ws, size_t ws_size,
                              hipStream_t stream) {
  const float* A = (const float*)d_in[0];
  const float* B = (const float*)d_in[1];
  const float* v = (const float*)d_in[2];
  float* C = (float*)d_ws;                                        // 64 MiB
  float* D = (float*)((char*)d_ws + (size_t)NBLK*SBAT*SBLK*SBLK*4); // +8 MiB
  float* out = (float*)d_out;

  pcr_phase1<<<(NBLK * SBAT) / 32, 256, 0, stream>>>(A, B, v, C, D);
  pcr_phase2<<<SBAT / 8, 64, 0, stream>>>(C, D, out);
}

// Round 2
// 66.495 us; speedup vs baseline: 5.9936x; 5.9936x over previous
//
#include <hip/hip_runtime.h>

#define NBLK 1024
#define SBAT 256
#define SBLK 8

// Phase 1: for each (block i, batch b) compute
//   C_i = A_i^{-1} B_{i-1}   (C_0 = 0)
//   d_i = A_i^{-1} v_i
// via Gauss-Jordan elimination with 8 lanes per system (lane = row),
// 8 systems per wave64. A is diagonally dominant -> no pivoting needed.
__global__ __launch_bounds__(256) void pcr_phase1(
    const float* __restrict__ A, const float* __restrict__ B,
    const float* __restrict__ v, float* __restrict__ C, float* __restrict__ D) {
  const int lane = threadIdx.x & 63;
  const int wib  = threadIdx.x >> 6;
  const int s = lane >> 3;       // system within wave (0..7)
  const int r = lane & 7;        // row (0..7)
  const long w  = (long)blockIdx.x * 4 + wib;  // global wave id
  const long t0 = w * 8;                        // first task of this wave
  const int i = (int)(t0 >> 8);                 // time block (t0/256)
  const int b = (int)(t0 & 255) + s;            // batch index
  const long sysid = (long)i * SBAT + b;

  float a[8], c[8], vv;
  {
    const float4* A4 = (const float4*)A;
    const long ab = (sysid * 8 + r) * 2;
    float4 lo = A4[ab], hi = A4[ab + 1];
    a[0]=lo.x; a[1]=lo.y; a[2]=lo.z; a[3]=lo.w;
    a[4]=hi.x; a[5]=hi.y; a[6]=hi.z; a[7]=hi.w;
  }
  if (i > 0) {
    const float4* B4 = (const float4*)B;
    const long bb = (((long)(i - 1) * SBAT + b) * 8 + r) * 2;
    float4 lo = B4[bb], hi = B4[bb + 1];
    c[0]=lo.x; c[1]=lo.y; c[2]=lo.z; c[3]=lo.w;
    c[4]=hi.x; c[5]=hi.y; c[6]=hi.z; c[7]=hi.w;
  } else {
    #pragma unroll
    for (int j = 0; j < 8; ++j) c[j] = 0.f;
  }
  vv = v[(long)b * (NBLK * SBLK) + i * SBLK + r];

  // Gauss-Jordan: reduce a -> I, c -> A^{-1}B, vv -> A^{-1}v.
  #pragma unroll
  for (int k = 0; k < 8; ++k) {
    const float piv  = __shfl(a[k], k, 8);
    const float invp = 1.0f / piv;
    if (r == k) {
      #pragma unroll
      for (int j = 0; j < 8; ++j) { a[j] *= invp; c[j] *= invp; }
      vv *= invp;
    }
    const float f  = (r == k) ? 0.0f : a[k];   // read before update
    const float vk = __shfl(vv, k, 8);
    #pragma unroll
    for (int j = 0; j < 8; ++j) {
      const float akj = __shfl(a[j], k, 8);    // scaled pivot row
      const float ckj = __shfl(c[j], k, 8);
      a[j] = fmaf(-f, akj, a[j]);
      c[j] = fmaf(-f, ckj, c[j]);
    }
    vv = fmaf(-f, vk, vv);
  }

  float4 lo, hi;
  lo.x=c[0]; lo.y=c[1]; lo.z=c[2]; lo.w=c[3];
  hi.x=c[4]; hi.y=c[5]; hi.z=c[6]; hi.w=c[7];
  float4* C4 = (float4*)C;
  const long cb = (sysid * 8 + r) * 2;
  C4[cb] = lo; C4[cb + 1] = hi;
  D[sysid * 8 + r] = vv;
}

// Phase 2: x_i = d_i - C_i x_{i-1}, parallelized over the time axis by
// chunking: NBLK split into CH chunks of L; each chunk starts from x=0 at
// (chunk_start - H) and runs H warm-up steps. Contraction ||C||~0.1 makes
// the truncation error ~0.1^H ~ 1e-16 (<< fp32 rounding). 8192 systems,
// 1024 waves. Static double-buffered prefetch (all reg indices const).
#define CL 32
#define CH_N (NBLK / CL)   // 32
#define HW 16              // warm-up steps
#define NB 8               // prefetch group size

__global__ __launch_bounds__(256) void pcr_phase2(
    const float* __restrict__ C, const float* __restrict__ D,
    float* __restrict__ out) {
  const int r = threadIdx.x & 7;
  const int g = blockIdx.x * 32 + (threadIdx.x >> 3);  // global system id
  const int b = g & (SBAT - 1);
  const int c = g >> 8;                                 // chunk id
  const int i_out   = c * CL;
  const int i_first = (c > 0) ? (i_out - HW) : 0;
  const int niter   = CL + ((c > 0) ? HW : 0);          // 48 or 32 (mult of 16)
  const int i_last  = i_out + CL - 1;

  const float4* C4 = (const float4*)C;

  float4 al[NB], ah[NB]; float ad[NB];
  float4 bl[NB], bh[NB]; float bd[NB];

#define LOADG(Pl, Ph, Pd, BASE)                                         \
  {                                                                     \
    _Pragma("unroll")                                                   \
    for (int j = 0; j < NB; ++j) {                                      \
      int ii = i_first + (BASE) + j;                                    \
      ii = (ii > i_last) ? i_last : ii;                                 \
      const long cb = (((long)ii * SBAT + b) * 8 + r) * 2;              \
      Pl[j] = C4[cb]; Ph[j] = C4[cb + 1];                               \
      Pd[j] = D[((long)ii * SBAT + b) * 8 + r];                         \
    }                                                                   \
  }

#define CONSUME(Pl, Ph, Pd, BASE)                                       \
  {                                                                     \
    _Pragma("unroll")                                                   \
    for (int j = 0; j < NB; ++j) {                                      \
      const int i = i_first + (BASE) + j;                               \
      const float4 cl = Pl[j], ch = Ph[j];                              \
      const float dd = Pd[j];                                           \
      const float x0=__shfl(xprev,0,8), x1=__shfl(xprev,1,8),           \
                  x2=__shfl(xprev,2,8), x3=__shfl(xprev,3,8),           \
                  x4=__shfl(xprev,4,8), x5=__shfl(xprev,5,8),           \
                  x6=__shfl(xprev,6,8), x7=__shfl(xprev,7,8);           \
      float acc0 = cl.x * x0;                                           \
      acc0 = fmaf(cl.z, x2, acc0);                                      \
      acc0 = fmaf(ch.x, x4, acc0);                                      \
      acc0 = fmaf(ch.z, x6, acc0);                                      \
      float acc1 = cl.y * x1;                                           \
      acc1 = fmaf(cl.w, x3, acc1);                                      \
      acc1 = fmaf(ch.y, x5, acc1);                                      \
      acc1 = fmaf(ch.w, x7, acc1);                                      \
      const float x = dd - acc0 - acc1;                                 \
      if (i >= i_out) out[(long)b * (NBLK * SBLK) + i * SBLK + r] = x;  \
      xprev = x;                                                        \
    }                                                                   \
  }

  float xprev = 0.f;
  LOADG(al, ah, ad, 0);
  for (int t = 0; t < niter; t += 2 * NB) {
    LOADG(bl, bh, bd, t + NB);
    CONSUME(al, ah, ad, t);
    LOADG(al, ah, ad, t + 2 * NB);
    CONSUME(bl, bh, bd, t + NB);
  }
}

extern "C" void kernel_launch(void* const* d_in, const int* in_sizes, int n_in,
                              void* d_out, int out_size, void* d_ws, size_t ws_size,
                              hipStream_t stream) {
  const float* A = (const float*)d_in[0];
  const float* B = (const float*)d_in[1];
  const float* v = (const float*)d_in[2];
  float* C = (float*)d_ws;                                          // 64 MiB
  float* D = (float*)((char*)d_ws + (size_t)NBLK*SBAT*SBLK*SBLK*4); // +8 MiB
  float* out = (float*)d_out;

  pcr_phase1<<<(NBLK * SBAT) / 32, 256, 0, stream>>>(A, B, v, C, D);
  pcr_phase2<<<(CH_N * SBAT) / 32, 256, 0, stream>>>(C, D, out);
}